// Round 1
// 339.159 us; speedup vs baseline: 1.1466x; 1.1466x over previous
//
#include <hip/hip_runtime.h>
#include <hip/hip_bf16.h>

#define N_PTS 65536
#define K_CB  8192
#define D_DIM 64
#define CAPS  63   // candidate slots per row; slot 63 holds the count

typedef float f32x4 __attribute__((ext_vector_type(4)));
typedef short s16x8 __attribute__((ext_vector_type(8)));

typedef __attribute__((address_space(1))) const unsigned int gu32;
typedef __attribute__((address_space(3))) unsigned int lu32;

__device__ __forceinline__ unsigned bfpack2(float a, float b) {
    union { __hip_bfloat162 h2; unsigned u; } cv;
    cv.h2 = __float22bfloat162_rn(make_float2(a, b));   // RNE pair cvt (v_cvt_pk_bf16_f32)
    return cv.u;
}

// async global->LDS, 16B/lane; LDS dest = wave-uniform base + lane*16
__device__ __forceinline__ void gl2lds16(const void* g, void* lds) {
    __builtin_amdgcn_global_load_lds((gu32*)g, (lu32*)lds, 16, 0, 0);
}

// DPP max within 16-lane rows (reduction domain = tx group, DPP-row aligned)
template <int CTRL>
__device__ __forceinline__ float dpp_fmax(float v) {
    int s = __builtin_amdgcn_update_dpp(0, __float_as_int(v), CTRL, 0xf, 0xf, true);
    return fmaxf(v, __int_as_float(s));
}

// ---- node 0: codebook fp32 -> bf16, stored pre-swizzled in LDS-image order ----
// image[k*64 + s*8 + e] = bf16(cb[k][(s ^ (k&7))*8 + e])  -- bit-identical bytes to
// the old in-kernel cbb fill, so coarse scores are unchanged.
__global__ __launch_bounds__(256) void vq_pack(
        const float* __restrict__ cb, unsigned short* __restrict__ cbswz) {
    int g = blockIdx.x * 256 + threadIdx.x;     // one thread per (row, slot-of-8)
    int row = g >> 3, s = g & 7;
    int u = (s ^ (row & 7)) * 8;
    const float4* p = (const float4*)(cb + (size_t)row * D_DIM + u);
    float4 a = p[0], b = p[1];
    uint4 pk;
    pk.x = bfpack2(a.x, a.y); pk.y = bfpack2(a.z, a.w);
    pk.z = bfpack2(b.x, b.y); pk.w = bfpack2(b.z, b.w);
    *(uint4*)(cbswz + (size_t)row * 64 + s * 8) = pk;
}

// ---- node 1: e2[K], x2[N] (numpy-pairwise exact) + per-block e2 maxes ----
__global__ __launch_bounds__(256) void vq_prep(
        const float* __restrict__ z, const float* __restrict__ cb,
        float* __restrict__ e2, float* __restrict__ x2, float* __restrict__ bmax) {
#pragma clang fp contract(off)
    __shared__ float sm[4];
    int b = blockIdx.x;
    int lane = threadIdx.x & 63;
    int wv = threadIdx.x >> 6;
    const float* src; float* dst; int row0;
    if (b < 128) { src = cb; dst = e2; row0 = b * 64 + wv * 16; }
    else         { src = z;  dst = x2; row0 = (b - 128) * 64 + wv * 16; }
    float lmax = 0.f;
    for (int r = 0; r < 16; ++r) {
        int row = row0 + r;
        float v = src[(size_t)row * D_DIM + lane];
        float w = v * v;
        float ra = w;
#pragma unroll
        for (int i = 1; i < 8; ++i) ra = ra + __shfl(w, lane + 8 * i, 64);
        float r0 = __shfl(ra, 0, 64), r1 = __shfl(ra, 1, 64),
              r2 = __shfl(ra, 2, 64), r3 = __shfl(ra, 3, 64),
              r4 = __shfl(ra, 4, 64), r5 = __shfl(ra, 5, 64),
              r6 = __shfl(ra, 6, 64), r7 = __shfl(ra, 7, 64);
        if (lane == 0) {
            float s = ((r0 + r1) + (r2 + r3)) + ((r4 + r5) + (r6 + r7));
            dst[row] = s;
            lmax = fmaxf(lmax, s);
        }
    }
    if (b < 128) {                 // block-uniform branch: syncthreads is safe
        if (lane == 0) sm[wv] = lmax;
        __syncthreads();
        if (threadIdx.x == 0)
            bmax[b] = fmaxf(fmaxf(sm[0], sm[1]), fmaxf(sm[2], sm[3]));
    }
}

// stage one 256-row codebook chunk (32 KB, pre-swizzled) + its e2 slice, async
__device__ __forceinline__ void stage_chunk(
        const unsigned short* __restrict__ cbswz, const float* __restrict__ e2,
        unsigned short* bufb, float* e2hb, int kc, int w, int l) {
    const char* gbase = (const char*)(cbswz + (size_t)kc * 256 * 64);
#pragma unroll
    for (int j = 0; j < 8; ++j) {
        int off = j * 4096 + w * 1024;               // wave-uniform LDS base
        gl2lds16(gbase + off + l * 16, (char*)bufb + off);
    }
    if (w == 0)                                       // 256 floats = 1 wave-instr
        gl2lds16(e2 + kc * 256 + l * 4, e2hb);
}

// ---- node 2: single-sweep coarse argmin with online candidate collection ----
// bias -e2/2 in MFMA C-init => t = -2*acc; min-t == max-acc.
// Collect acc >= prefixMax - W/2 (superset guarantee); chunk 0 revisited at end.
// v2: pre-packed bf16 codebook staged via global_load_lds into a double-buffered
// 2x32KB LDS ring (buffer 0 reuses the z-tile LDS, which is dead after the
// A-frags are register-resident). One barrier per chunk; loads issued a full
// compute phase ahead of their drain.
__global__ __launch_bounds__(256, 2) void vq_coarse(
        const float* __restrict__ z, const unsigned short* __restrict__ cbswz,
        const float* __restrict__ e2, const float* __restrict__ x2,
        const float* __restrict__ bmax, int* __restrict__ cand) {
    // pool[0]    : z tile (bf16, swizzled) -- only until A-frags are loaded
    // pool[0..1] : cbb buffer 0 (32 KB);  pool[2..3] : cbb buffer 1 (32 KB)
    __shared__ __align__(16) unsigned short pool[4][128 * 64];   // 64 KB
    __shared__ __align__(16) float e2h[2][256];                  // 2 KB
    __shared__ int cntS[128];
    const int tid = threadIdx.x;
    const int w = tid >> 6, l = tid & 63, tx = l & 15, q = l >> 4;
    const int n0 = blockIdx.x * 128;

    if (tid < 128) cntS[tid] = 0;

    // stage z tile fp32->bf16, swizzled (one-time; proven conflict-free layout)
#pragma unroll
    for (int i = 0; i < 4; ++i) {
        int lin = tid + 256 * i;
        int row = lin >> 3, u = lin & 7;
        const float4* p = (const float4*)(z + (size_t)(n0 + row) * D_DIM + u * 8);
        float4 a = p[0], b2 = p[1];
        uint4 pk;
        pk.x = bfpack2(a.x, a.y);   pk.y = bfpack2(a.z, a.w);
        pk.z = bfpack2(b2.x, b2.y); pk.w = bfpack2(b2.z, b2.w);
        *(uint4*)&pool[0][row * 64 + ((u ^ (row & 7)) * 8)] = pk;
    }

    float e2m;   // global e2max from prep's per-block maxes
    {
        float v = fmaxf(bmax[l], bmax[l + 64]);
#pragma unroll
        for (int m = 1; m < 64; m <<= 1) v = fmaxf(v, __shfl_xor(v, m, 64));
        e2m = v;
    }

    float halfW[8], A[8], M[8];
#pragma unroll
    for (int i = 0; i < 8; ++i) {
        int row = n0 + w * 32 + (i >> 2) * 16 + q * 4 + (i & 3);
        halfW[i] = 0.0175f * sqrtf(x2[row] * e2m) + 1e-4f;   // W/2, R4-proven constant
        A[i] = 3.0e38f;      // no collection during first chunk
        M[i] = -3.4e38f;
    }

    __syncthreads();                       // z tile visible to all waves
    s16x8 afr[2][2];                       // A-frags register-resident for whole kernel
#pragma unroll
    for (int rt = 0; rt < 2; ++rt)
#pragma unroll
        for (int ks = 0; ks < 2; ++ks) {
            int row = w * 32 + rt * 16 + tx;
            afr[rt][ks] = *(const s16x8*)&pool[0][row * 64 + (((ks * 4 + q) ^ (tx & 7)) * 8)];
        }
    __syncthreads();                       // all waves done with z tile -> pool[0] reusable

    stage_chunk(cbswz, e2, &pool[0][0], e2h[0], 0, w, l);
    __syncthreads();                       // implicit vmcnt(0): chunk 0 resident

    for (int it = 0; it < 33; ++it) {      // 32 chunks + chunk-0 revisit
        const int kc = (it < 32) ? it : 0;
        const int cur = it & 1;
        if (it < 32)                       // issue next-chunk stage BEFORE compute
            stage_chunk(cbswz, e2, &pool[((it + 1) & 1) * 2][0], e2h[(it + 1) & 1],
                        (it + 1 < 32) ? it + 1 : 0, w, l);

        const unsigned short* cbb = &pool[cur * 2][0];
        const float* e2c = e2h[cur];
        const bool collect = (it > 0);
        for (int ct = 0; ct < 16; ++ct) {
            int crow = ct * 16 + tx;
            float bias = -0.5f * e2c[crow];
            s16x8 b0 = *(const s16x8*)&cbb[crow * 64 + ((q ^ (tx & 7)) * 8)];
            s16x8 b1 = *(const s16x8*)&cbb[crow * 64 + (((4 + q) ^ (tx & 7)) * 8)];
            int kglob = kc * 256 + crow;
#pragma unroll
            for (int rt = 0; rt < 2; ++rt) {
                f32x4 acc = {bias, bias, bias, bias};
                acc = __builtin_amdgcn_mfma_f32_16x16x32_bf16(afr[rt][0], b0, acc, 0, 0, 0);
                acc = __builtin_amdgcn_mfma_f32_16x16x32_bf16(afr[rt][1], b1, acc, 0, 0, 0);
                const int i0 = rt * 4;
                M[i0 + 0] = fmaxf(M[i0 + 0], acc[0]);
                M[i0 + 1] = fmaxf(M[i0 + 1], acc[1]);
                M[i0 + 2] = fmaxf(M[i0 + 2], acc[2]);
                M[i0 + 3] = fmaxf(M[i0 + 3], acc[3]);
                // single divergent branch per quad; identical fp predicates re-checked inside
                bool any = (acc[0] >= A[i0 + 0]) | (acc[1] >= A[i0 + 1]) |
                           (acc[2] >= A[i0 + 2]) | (acc[3] >= A[i0 + 3]);
                if (collect && any) {
#pragma unroll
                    for (int r = 0; r < 4; ++r) {
                        if (acc[r] >= A[i0 + r]) {
                            int row = w * 32 + rt * 16 + q * 4 + r;
                            int slot = atomicAdd(&cntS[row], 1);
                            if (slot < CAPS)
                                cand[(size_t)(n0 + row) * 64 + slot] = kglob;
                        }
                    }
                }
            }
        }
        if (it < 32) {   // cross-lane (tx) prefix max via DPP -> new threshold
#pragma unroll
            for (int i = 0; i < 8; ++i) {
                float v = M[i];
                v = dpp_fmax<0xB1>(v);    // quad_perm [1,0,3,2]  (xor 1)
                v = dpp_fmax<0x4E>(v);    // quad_perm [2,3,0,1]  (xor 2)
                v = dpp_fmax<0x124>(v);   // row_ror:4  (combine quads)
                v = dpp_fmax<0x128>(v);   // row_ror:8  (full 16-lane max)
                M[i] = v;
                A[i] = v - halfW[i];
            }
        }
        __syncthreads();   // drains vmcnt (stage issued ~full phase ago) + buffer handoff
    }
    if (tid < 128) cand[(size_t)(n0 + tid) * 64 + 63] = cntS[tid];
}

// ---- exact fp32 rescore: bit-identical to the round-3/4 passing pipeline ----
__device__ __forceinline__ float exact_score(const float* zr, const float* __restrict__ cb,
                                             const float* __restrict__ e2, float x2v, int k) {
    const float4* c4 = (const float4*)(cb + (size_t)k * D_DIM);
    float g = 0.f;
#pragma unroll
    for (int j = 0; j < 16; ++j) {
        float4 v = c4[j];
        g = fmaf(zr[4 * j + 0], v.x, g);
        g = fmaf(zr[4 * j + 1], v.y, g);
        g = fmaf(zr[4 * j + 2], v.z, g);
        g = fmaf(zr[4 * j + 3], v.w, g);
    }
    return fmaf(-2.f, g, x2v) + e2[k];
}

// ---- node 3: rescore + gather + straight-through write + loss partials ----
__global__ __launch_bounds__(256, 2) void vq_rescore(
        const float* __restrict__ z, const float* __restrict__ cb,
        const float* __restrict__ e2, const float* __restrict__ x2,
        int* __restrict__ slots, float* __restrict__ idx_out,
        float* __restrict__ partials) {
    int tid = threadIdx.x;
    int n = blockIdx.x * 256 + tid;
    float zr[64];
    const float4* z4 = (const float4*)(z + (size_t)n * D_DIM);
#pragma unroll
    for (int i = 0; i < 16; ++i) {
        float4 v = z4[i];
        zr[4 * i] = v.x; zr[4 * i + 1] = v.y; zr[4 * i + 2] = v.z; zr[4 * i + 3] = v.w;
    }
    float x2v = x2[n];
    int cnt = slots[(size_t)n * 64 + 63];
    float bs = 3.4e38f; int bk = 0x7fffffff;
    if (cnt <= CAPS) {
        // 2-way unroll for memory-level parallelism; sequential merge keeps
        // exact (score, index) lexicographic-min semantics -> order-independent.
        int i = 0;
        for (; i + 1 < cnt; i += 2) {
            int ka = slots[(size_t)n * 64 + i];
            int kb = slots[(size_t)n * 64 + i + 1];
            float sa = exact_score(zr, cb, e2, x2v, ka);
            float sb = exact_score(zr, cb, e2, x2v, kb);
            if (sa < bs || (sa == bs && ka < bk)) { bs = sa; bk = ka; }
            if (sb < bs || (sb == bs && kb < bk)) { bs = sb; bk = kb; }
        }
        if (i < cnt) {
            int k = slots[(size_t)n * 64 + i];
            float s = exact_score(zr, cb, e2, x2v, k);
            if (s < bs || (s == bs && k < bk)) { bs = s; bk = k; }
        }
    }
    // wave-cooperative full scan for overflowed rows (cheap, ~never taken)
    unsigned long long mask = __ballot(cnt > CAPS);
    while (mask) {
        int src = __ffsll((long long)mask) - 1;
        mask &= (mask - 1);
        int rown = __shfl(n, src, 64);
        float x2s = __shfl(x2v, src, 64);
        float zs[64];
        const float4* zz = (const float4*)(z + (size_t)rown * D_DIM);
#pragma unroll
        for (int i = 0; i < 16; ++i) {
            float4 v = zz[i];
            zs[4 * i] = v.x; zs[4 * i + 1] = v.y; zs[4 * i + 2] = v.z; zs[4 * i + 3] = v.w;
        }
        float fb = 3.4e38f; int fk = 0x7fffffff;
        for (int k = (tid & 63); k < K_CB; k += 64) {
            float s = exact_score(zs, cb, e2, x2s, k);
            if (s < fb || (s == fb && k < fk)) { fb = s; fk = k; }
        }
#pragma unroll
        for (int m = 1; m < 64; m <<= 1) {
            float ov = __shfl_xor(fb, m, 64);
            int   ok = __shfl_xor(fk, m, 64);
            if (ov < fb || (ov == fb && ok < fk)) { fb = ov; fk = ok; }
        }
        if ((tid & 63) == src) { bs = fb; bk = fk; }
    }
    idx_out[n] = (float)bk;
    __threadfence_block();   // all slot reads drained before aliased zq writes

    float lsum = 0.f;
    const float4* c4 = (const float4*)(cb + (size_t)bk * D_DIM);
    float4* o4 = (float4*)((float*)slots + (size_t)n * 64);   // own slot, float view
#pragma unroll
    for (int j = 0; j < 16; ++j) {
        float4 c = c4[j];
        float4 o;
        float d0 = c.x - zr[4 * j];     o.x = zr[4 * j]     + d0;
        float d1 = c.y - zr[4 * j + 1]; o.y = zr[4 * j + 1] + d1;
        float d2 = c.z - zr[4 * j + 2]; o.z = zr[4 * j + 2] + d2;
        float d3 = c.w - zr[4 * j + 3]; o.w = zr[4 * j + 3] + d3;
        lsum += d0 * d0 + d1 * d1 + d2 * d2 + d3 * d3;
        o4[j] = o;
    }
    __shared__ float red[256];
    red[tid] = lsum;
    __syncthreads();
    for (int s = 128; s > 0; s >>= 1) {
        if (tid < s) red[tid] += red[tid + s];
        __syncthreads();
    }
    if (tid == 0) partials[blockIdx.x] = red[0];
}

// ---- node 4: final loss ----
__global__ void vq_final(const float* __restrict__ partials, float* __restrict__ loss_out) {
    __shared__ float red[256];
    int tid = threadIdx.x;
    red[tid] = partials[tid];
    __syncthreads();
    for (int s = 128; s > 0; s >>= 1) {
        if (tid < s) red[tid] += red[tid + s];
        __syncthreads();
    }
    if (tid == 0) *loss_out = 1.25f * red[0] / (float)(N_PTS * D_DIM);
}

extern "C" void kernel_launch(void* const* d_in, const int* in_sizes, int n_in,
                              void* d_out, int out_size, void* d_ws, size_t ws_size,
                              hipStream_t stream) {
    const float* z  = (const float*)d_in[0];
    const float* cb = (const float*)d_in[1];
    float* out      = (float*)d_out;
    float* zq_out   = out;                          // [N*64]; doubles as cand slots
    float* loss_out = out + (size_t)N_PTS * D_DIM;  // [1]
    float* idx_out  = loss_out + 1;                 // [N]; [0..127] doubles as bmax scratch

    // workspace: partials(256f) | e2(K f) | x2(N f) | cbswz(K*64 bf16, 1 MB)
    // total ~1.35 MB (was ~296 KB)
    float* wsf = (float*)d_ws;
    float* partials = wsf;
    float* e2 = wsf + 256;
    float* x2 = wsf + 256 + K_CB;
    unsigned short* cbswz = (unsigned short*)(wsf + 256 + K_CB + N_PTS);  // 16B-aligned

    int* cand = (int*)zq_out;
    float* bmax = idx_out;                          // overwritten by rescore afterwards

    vq_pack   <<<K_CB * 8 / 256, 256, 0, stream>>>(cb, cbswz);
    vq_prep   <<<128 + N_PTS / 64, 256, 0, stream>>>(z, cb, e2, x2, bmax);
    vq_coarse <<<N_PTS / 128, 256, 0, stream>>>(z, cbswz, e2, x2, bmax, cand);
    vq_rescore<<<N_PTS / 256, 256, 0, stream>>>(z, cb, e2, x2, cand, idx_out, partials);
    vq_final  <<<1, 256, 0, stream>>>(partials, loss_out);
}

// Round 2
// 275.870 us; speedup vs baseline: 1.4097x; 1.2294x over previous
//
#include <hip/hip_runtime.h>
#include <hip/hip_bf16.h>

#define N_PTS 65536
#define K_CB  8192
#define D_DIM 64
#define CAPS  63   // candidate slots per row; slot 63 holds the count

typedef float f32x4 __attribute__((ext_vector_type(4)));
typedef short s16x8 __attribute__((ext_vector_type(8)));

typedef __attribute__((address_space(1))) const unsigned int gu32;
typedef __attribute__((address_space(3))) unsigned int lu32;

__device__ __forceinline__ unsigned bfpack2(float a, float b) {
    union { __hip_bfloat162 h2; unsigned u; } cv;
    cv.h2 = __float22bfloat162_rn(make_float2(a, b));   // RNE pair cvt (v_cvt_pk_bf16_f32)
    return cv.u;
}

// async global->LDS, 16B/lane; LDS dest = wave-uniform base + lane*16
__device__ __forceinline__ void gl2lds16(const void* g, void* lds) {
    __builtin_amdgcn_global_load_lds((gu32*)g, (lu32*)lds, 16, 0, 0);
}

// DPP max within 16-lane rows (reduction domain = tx group, DPP-row aligned)
template <int CTRL>
__device__ __forceinline__ float dpp_fmax(float v) {
    int s = __builtin_amdgcn_update_dpp(0, __float_as_int(v), CTRL, 0xf, 0xf, true);
    return fmaxf(v, __int_as_float(s));
}

// ---- node 0: codebook fp32 -> bf16, stored pre-swizzled in LDS-image order ----
// image[k*64 + s*8 + e] = bf16(cb[k][(s ^ (k&7))*8 + e])  -- bit-identical bytes to
// the original in-kernel cbb fill, so coarse scores are unchanged.
__global__ __launch_bounds__(256) void vq_pack(
        const float* __restrict__ cb, unsigned short* __restrict__ cbswz) {
    int g = blockIdx.x * 256 + threadIdx.x;     // one thread per (row, slot-of-8)
    int row = g >> 3, s = g & 7;
    int u = (s ^ (row & 7)) * 8;
    const float4* p = (const float4*)(cb + (size_t)row * D_DIM + u);
    float4 a = p[0], b = p[1];
    uint4 pk;
    pk.x = bfpack2(a.x, a.y); pk.y = bfpack2(a.z, a.w);
    pk.z = bfpack2(b.x, b.y); pk.w = bfpack2(b.z, b.w);
    *(uint4*)(cbswz + (size_t)row * 64 + s * 8) = pk;
}

// ---- node 1: e2[K], x2[N] (numpy-pairwise exact) + per-block e2 maxes ----
__global__ __launch_bounds__(256) void vq_prep(
        const float* __restrict__ z, const float* __restrict__ cb,
        float* __restrict__ e2, float* __restrict__ x2, float* __restrict__ bmax) {
#pragma clang fp contract(off)
    __shared__ float sm[4];
    int b = blockIdx.x;
    int lane = threadIdx.x & 63;
    int wv = threadIdx.x >> 6;
    const float* src; float* dst; int row0;
    if (b < 128) { src = cb; dst = e2; row0 = b * 64 + wv * 16; }
    else         { src = z;  dst = x2; row0 = (b - 128) * 64 + wv * 16; }
    float lmax = 0.f;
    for (int r = 0; r < 16; ++r) {
        int row = row0 + r;
        float v = src[(size_t)row * D_DIM + lane];
        float w = v * v;
        float ra = w;
#pragma unroll
        for (int i = 1; i < 8; ++i) ra = ra + __shfl(w, lane + 8 * i, 64);
        float r0 = __shfl(ra, 0, 64), r1 = __shfl(ra, 1, 64),
              r2 = __shfl(ra, 2, 64), r3 = __shfl(ra, 3, 64),
              r4 = __shfl(ra, 4, 64), r5 = __shfl(ra, 5, 64),
              r6 = __shfl(ra, 6, 64), r7 = __shfl(ra, 7, 64);
        if (lane == 0) {
            float s = ((r0 + r1) + (r2 + r3)) + ((r4 + r5) + (r6 + r7));
            dst[row] = s;
            lmax = fmaxf(lmax, s);
        }
    }
    if (b < 128) {                 // block-uniform branch: syncthreads is safe
        if (lane == 0) sm[wv] = lmax;
        __syncthreads();
        if (threadIdx.x == 0)
            bmax[b] = fmaxf(fmaxf(sm[0], sm[1]), fmaxf(sm[2], sm[3]));
    }
}

// stage one 256-row codebook chunk (32 KB, pre-swizzled) + its e2 slice, async.
// 8 waves: each wave covers 1 KB per j, 4 j-steps -> 32 KB.
__device__ __forceinline__ void stage_chunk(
        const unsigned short* __restrict__ cbswz, const float* __restrict__ e2,
        unsigned short* bufb, float* e2hb, int kc, int w, int l) {
    const char* gbase = (const char*)(cbswz + (size_t)kc * 256 * 64);
#pragma unroll
    for (int j = 0; j < 4; ++j) {
        int off = j * 8192 + w * 1024;               // wave-uniform LDS base
        gl2lds16(gbase + off + l * 16, (char*)bufb + off);
    }
    if (w == 0)                                       // 256 floats = 1 wave-instr
        gl2lds16(e2 + kc * 256 + l * 4, e2hb);
}

// ---- node 2: single-sweep coarse argmin with online candidate collection ----
// bias -e2/2 in MFMA C-init => t = -2*acc; min-t == max-acc.
// Collect acc >= prefixMax - W/2 (superset guarantee); chunk 0 revisited at end.
// v3: 512-thread blocks (8 waves, 16 z-rows each) -> 16 waves/CU at the same
// 2-blocks/CU LDS footprint; quad-max branch-entry filter (identical candidate
// set: exact per-element predicates re-checked inside).
__global__ __launch_bounds__(512, 4) void vq_coarse(
        const float* __restrict__ z, const unsigned short* __restrict__ cbswz,
        const float* __restrict__ e2, const float* __restrict__ x2,
        const float* __restrict__ bmax, int* __restrict__ cand) {
    // pool[0]    : z tile (bf16, swizzled, 16 KB) -- only until A-frags are loaded
    // pool[0..1] : cbb buffer 0 (32 KB);  pool[2..3] : cbb buffer 1 (32 KB)
    __shared__ __align__(16) unsigned short pool[4][128 * 64];   // 64 KB
    __shared__ __align__(16) float e2h[2][256];                  // 2 KB
    __shared__ int cntS[128];
    const int tid = threadIdx.x;
    const int w = tid >> 6, l = tid & 63, tx = l & 15, q = l >> 4;
    const int n0 = blockIdx.x * 128;

    if (tid < 128) cntS[tid] = 0;

    // stage z tile fp32->bf16, swizzled (one-time; proven conflict-free layout)
#pragma unroll
    for (int i = 0; i < 2; ++i) {
        int lin = tid + 512 * i;
        int row = lin >> 3, u = lin & 7;
        const float4* p = (const float4*)(z + (size_t)(n0 + row) * D_DIM + u * 8);
        float4 a = p[0], b2 = p[1];
        uint4 pk;
        pk.x = bfpack2(a.x, a.y);   pk.y = bfpack2(a.z, a.w);
        pk.z = bfpack2(b2.x, b2.y); pk.w = bfpack2(b2.z, b2.w);
        *(uint4*)&pool[0][row * 64 + ((u ^ (row & 7)) * 8)] = pk;
    }

    float e2m;   // global e2max from prep's per-block maxes
    {
        float v = fmaxf(bmax[l], bmax[l + 64]);
#pragma unroll
        for (int m = 1; m < 64; m <<= 1) v = fmaxf(v, __shfl_xor(v, m, 64));
        e2m = v;
    }

    float halfW[4], A[4], M[4];
#pragma unroll
    for (int i = 0; i < 4; ++i) {
        int row = n0 + w * 16 + q * 4 + i;
        halfW[i] = 0.0175f * sqrtf(x2[row] * e2m) + 1e-4f;   // W/2, R4-proven constant
        A[i] = 3.0e38f;      // no collection during first chunk
        M[i] = -3.4e38f;
    }
    float Amin = 3.0e38f;

    __syncthreads();                       // z tile visible to all waves
    s16x8 afr[2];                          // A-frags register-resident for whole kernel
#pragma unroll
    for (int ks = 0; ks < 2; ++ks) {
        int row = w * 16 + tx;
        afr[ks] = *(const s16x8*)&pool[0][row * 64 + (((ks * 4 + q) ^ (tx & 7)) * 8)];
    }
    __syncthreads();                       // all waves done with z tile -> pool[0] reusable

    stage_chunk(cbswz, e2, &pool[0][0], e2h[0], 0, w, l);
    __syncthreads();                       // implicit vmcnt(0): chunk 0 resident

    for (int it = 0; it < 33; ++it) {      // 32 chunks + chunk-0 revisit
        const int kc = (it < 32) ? it : 0;
        const int cur = it & 1;
        if (it < 32)                       // issue next-chunk stage BEFORE compute
            stage_chunk(cbswz, e2, &pool[((it + 1) & 1) * 2][0], e2h[(it + 1) & 1],
                        (it + 1 < 32) ? it + 1 : 0, w, l);

        const unsigned short* cbb = &pool[cur * 2][0];
        const float* e2c = e2h[cur];
#pragma unroll 4
        for (int ct = 0; ct < 16; ++ct) {
            int crow = ct * 16 + tx;
            float bias = -0.5f * e2c[crow];
            s16x8 b0 = *(const s16x8*)&cbb[crow * 64 + ((q ^ (tx & 7)) * 8)];
            s16x8 b1 = *(const s16x8*)&cbb[crow * 64 + (((4 + q) ^ (tx & 7)) * 8)];
            f32x4 acc = {bias, bias, bias, bias};
            acc = __builtin_amdgcn_mfma_f32_16x16x32_bf16(afr[0], b0, acc, 0, 0, 0);
            acc = __builtin_amdgcn_mfma_f32_16x16x32_bf16(afr[1], b1, acc, 0, 0, 0);
            M[0] = fmaxf(M[0], acc[0]);
            M[1] = fmaxf(M[1], acc[1]);
            M[2] = fmaxf(M[2], acc[2]);
            M[3] = fmaxf(M[3], acc[3]);
            // quad-max entry filter: superset of any(acc[r] >= A[r]); exact
            // per-element predicates re-checked inside -> identical candidate set.
            float amax = fmaxf(fmaxf(acc[0], acc[1]), fmaxf(acc[2], acc[3]));
            if (amax >= Amin) {            // rare; false during it==0 (Amin=3e38)
                int kglob = kc * 256 + crow;
#pragma unroll
                for (int r = 0; r < 4; ++r) {
                    if (acc[r] >= A[r]) {
                        int row = w * 16 + q * 4 + r;
                        int slot = atomicAdd(&cntS[row], 1);
                        if (slot < CAPS)
                            cand[(size_t)(n0 + row) * 64 + slot] = kglob;
                    }
                }
            }
        }
        if (it < 32) {   // cross-lane (tx) prefix max via DPP -> new threshold
#pragma unroll
            for (int i = 0; i < 4; ++i) {
                float v = M[i];
                v = dpp_fmax<0xB1>(v);    // quad_perm [1,0,3,2]  (xor 1)
                v = dpp_fmax<0x4E>(v);    // quad_perm [2,3,0,1]  (xor 2)
                v = dpp_fmax<0x124>(v);   // row_ror:4  (combine quads)
                v = dpp_fmax<0x128>(v);   // row_ror:8  (full 16-lane max)
                M[i] = v;
                A[i] = v - halfW[i];
            }
            Amin = fminf(fminf(A[0], A[1]), fminf(A[2], A[3]));
        }
        __syncthreads();   // drains vmcnt (stage issued ~full phase ago) + buffer handoff
    }
    if (tid < 128) cand[(size_t)(n0 + tid) * 64 + 63] = cntS[tid];
}

// ---- exact fp32 rescore: bit-identical to the round-3/4 passing pipeline ----
__device__ __forceinline__ float exact_score(const float* zr, const float* __restrict__ cb,
                                             const float* __restrict__ e2, float x2v, int k) {
    const float4* c4 = (const float4*)(cb + (size_t)k * D_DIM);
    float g = 0.f;
#pragma unroll
    for (int j = 0; j < 16; ++j) {
        float4 v = c4[j];
        g = fmaf(zr[4 * j + 0], v.x, g);
        g = fmaf(zr[4 * j + 1], v.y, g);
        g = fmaf(zr[4 * j + 2], v.z, g);
        g = fmaf(zr[4 * j + 3], v.w, g);
    }
    return fmaf(-2.f, g, x2v) + e2[k];
}

// ---- node 3: rescore + gather + straight-through write + loss partials ----
__global__ __launch_bounds__(256, 2) void vq_rescore(
        const float* __restrict__ z, const float* __restrict__ cb,
        const float* __restrict__ e2, const float* __restrict__ x2,
        int* __restrict__ slots, float* __restrict__ idx_out,
        float* __restrict__ partials) {
    int tid = threadIdx.x;
    int n = blockIdx.x * 256 + tid;
    float zr[64];
    const float4* z4 = (const float4*)(z + (size_t)n * D_DIM);
#pragma unroll
    for (int i = 0; i < 16; ++i) {
        float4 v = z4[i];
        zr[4 * i] = v.x; zr[4 * i + 1] = v.y; zr[4 * i + 2] = v.z; zr[4 * i + 3] = v.w;
    }
    float x2v = x2[n];
    int cnt = slots[(size_t)n * 64 + 63];
    float bs = 3.4e38f; int bk = 0x7fffffff;
    if (cnt <= CAPS) {
        // 2-way unroll for memory-level parallelism; sequential merge keeps
        // exact (score, index) lexicographic-min semantics -> order-independent.
        int i = 0;
        for (; i + 1 < cnt; i += 2) {
            int ka = slots[(size_t)n * 64 + i];
            int kb = slots[(size_t)n * 64 + i + 1];
            float sa = exact_score(zr, cb, e2, x2v, ka);
            float sb = exact_score(zr, cb, e2, x2v, kb);
            if (sa < bs || (sa == bs && ka < bk)) { bs = sa; bk = ka; }
            if (sb < bs || (sb == bs && kb < bk)) { bs = sb; bk = kb; }
        }
        if (i < cnt) {
            int k = slots[(size_t)n * 64 + i];
            float s = exact_score(zr, cb, e2, x2v, k);
            if (s < bs || (s == bs && k < bk)) { bs = s; bk = k; }
        }
    }
    // wave-cooperative full scan for overflowed rows (cheap, ~never taken)
    unsigned long long mask = __ballot(cnt > CAPS);
    while (mask) {
        int src = __ffsll((long long)mask) - 1;
        mask &= (mask - 1);
        int rown = __shfl(n, src, 64);
        float x2s = __shfl(x2v, src, 64);
        float zs[64];
        const float4* zz = (const float4*)(z + (size_t)rown * D_DIM);
#pragma unroll
        for (int i = 0; i < 16; ++i) {
            float4 v = zz[i];
            zs[4 * i] = v.x; zs[4 * i + 1] = v.y; zs[4 * i + 2] = v.z; zs[4 * i + 3] = v.w;
        }
        float fb = 3.4e38f; int fk = 0x7fffffff;
        for (int k = (tid & 63); k < K_CB; k += 64) {
            float s = exact_score(zs, cb, e2, x2s, k);
            if (s < fb || (s == fb && k < fk)) { fb = s; fk = k; }
        }
#pragma unroll
        for (int m = 1; m < 64; m <<= 1) {
            float ov = __shfl_xor(fb, m, 64);
            int   ok = __shfl_xor(fk, m, 64);
            if (ov < fb || (ov == fb && ok < fk)) { fb = ov; fk = ok; }
        }
        if ((tid & 63) == src) { bs = fb; bk = fk; }
    }
    idx_out[n] = (float)bk;
    __threadfence_block();   // all slot reads drained before aliased zq writes

    float lsum = 0.f;
    const float4* c4 = (const float4*)(cb + (size_t)bk * D_DIM);
    float4* o4 = (float4*)((float*)slots + (size_t)n * 64);   // own slot, float view
#pragma unroll
    for (int j = 0; j < 16; ++j) {
        float4 c = c4[j];
        float4 o;
        float d0 = c.x - zr[4 * j];     o.x = zr[4 * j]     + d0;
        float d1 = c.y - zr[4 * j + 1]; o.y = zr[4 * j + 1] + d1;
        float d2 = c.z - zr[4 * j + 2]; o.z = zr[4 * j + 2] + d2;
        float d3 = c.w - zr[4 * j + 3]; o.w = zr[4 * j + 3] + d3;
        lsum += d0 * d0 + d1 * d1 + d2 * d2 + d3 * d3;
        o4[j] = o;
    }
    __shared__ float red[256];
    red[tid] = lsum;
    __syncthreads();
    for (int s = 128; s > 0; s >>= 1) {
        if (tid < s) red[tid] += red[tid + s];
        __syncthreads();
    }
    if (tid == 0) partials[blockIdx.x] = red[0];
}

// ---- node 4: final loss ----
__global__ void vq_final(const float* __restrict__ partials, float* __restrict__ loss_out) {
    __shared__ float red[256];
    int tid = threadIdx.x;
    red[tid] = partials[tid];
    __syncthreads();
    for (int s = 128; s > 0; s >>= 1) {
        if (tid < s) red[tid] += red[tid + s];
        __syncthreads();
    }
    if (tid == 0) *loss_out = 1.25f * red[0] / (float)(N_PTS * D_DIM);
}

extern "C" void kernel_launch(void* const* d_in, const int* in_sizes, int n_in,
                              void* d_out, int out_size, void* d_ws, size_t ws_size,
                              hipStream_t stream) {
    const float* z  = (const float*)d_in[0];
    const float* cb = (const float*)d_in[1];
    float* out      = (float*)d_out;
    float* zq_out   = out;                          // [N*64]; doubles as cand slots
    float* loss_out = out + (size_t)N_PTS * D_DIM;  // [1]
    float* idx_out  = loss_out + 1;                 // [N]; [0..127] doubles as bmax scratch

    // workspace: partials(256f) | e2(K f) | x2(N f) | cbswz(K*64 bf16, 1 MB)
    float* wsf = (float*)d_ws;
    float* partials = wsf;
    float* e2 = wsf + 256;
    float* x2 = wsf + 256 + K_CB;
    unsigned short* cbswz = (unsigned short*)(wsf + 256 + K_CB + N_PTS);  // 16B-aligned

    int* cand = (int*)zq_out;
    float* bmax = idx_out;                          // overwritten by rescore afterwards

    vq_pack   <<<K_CB * 8 / 256, 256, 0, stream>>>(cb, cbswz);
    vq_prep   <<<128 + N_PTS / 64, 256, 0, stream>>>(z, cb, e2, x2, bmax);
    vq_coarse <<<N_PTS / 128, 512, 0, stream>>>(z, cbswz, e2, x2, bmax, cand);
    vq_rescore<<<N_PTS / 256, 256, 0, stream>>>(z, cb, e2, x2, cand, idx_out, partials);
    vq_final  <<<1, 256, 0, stream>>>(partials, loss_out);
}